// Round 6
// baseline (1381.062 us; speedup 1.0000x reference)
//
#include <hip/hip_runtime.h>

#define NN 20000
#define NE 200000
#define NG 512

constexpr int EB = 64;   // edges staged per batch

typedef __attribute__((address_space(1))) const unsigned int gas_u32;
typedef __attribute__((address_space(3))) unsigned int las_u32;

// async global->LDS DMA, 16 B per lane; lds dest = wave-uniform base + lane*16
__device__ __forceinline__ void gl_lds16(const float4* g, float4* l){
  __builtin_amdgcn_global_load_lds((gas_u32*)(const void*)g, (las_u32*)(void*)l, 16, 0, 0);
}

__device__ __forceinline__ int lowerb(const int* a, int n, int v){
  int lo=0, hi=n;
  while(lo<hi){ int m=(lo+hi)>>1; if(a[m]<v) lo=m+1; else hi=m; }
  return lo;
}

// ---------------- counting sort by tgt -> CSR ----------------
__global__ void k_count(const int* __restrict__ tgt, int* __restrict__ cnt){
  int e = blockIdx.x*blockDim.x + threadIdx.x;
  if(e<NE) atomicAdd(&cnt[tgt[e]], 1);
}

__global__ void k_scan(const int* __restrict__ cnt, int* __restrict__ row_start){
  __shared__ int part[1024];
  int t = threadIdx.x;
  const int CH = (NN + 1023)/1024; // 20
  int i0 = t*CH;
  int s = 0;
  for(int j=0;j<CH;j++){ int i=i0+j; if(i<NN) s += cnt[i]; }
  part[t] = s; __syncthreads();
  for(int d=1; d<1024; d<<=1){
    int v = (t>=d) ? part[t-d] : 0;
    __syncthreads();
    part[t] += v;
    __syncthreads();
  }
  int run = (t==0) ? 0 : part[t-1];
  for(int j=0;j<CH;j++){ int i=i0+j; if(i<NN){ row_start[i]=run; run += cnt[i]; } }
  if(t==0) row_start[NN] = part[1023];
}

__global__ void k_place(const int* __restrict__ src, const int* __restrict__ tgt,
                        const int* __restrict__ row_start, int* __restrict__ cur,
                        int* __restrict__ es_src, int* __restrict__ es_pos){
  int e = blockIdx.x*blockDim.x + threadIdx.x;
  if(e>=NE) return;
  int n = tgt[e];
  int pos = row_start[n] + atomicAdd(&cur[n],1);
  es_src[pos] = src[e];
  es_pos[e] = pos;
}

__global__ void k_gatherea(const float* __restrict__ ea, const int* __restrict__ es_pos,
                           float* __restrict__ es_ea){
  int e = blockIdx.x*blockDim.x + threadIdx.x;
  if(e>=NE) return;
  int p = es_pos[e];
  const float4* s = (const float4*)ea + (size_t)e*4;
  float4* d = (float4*)es_ea + (size_t)p*4;
  d[0]=s[0]; d[1]=s[1]; d[2]=s[2]; d[3]=s[3];
}

// ---------------- H = relu(es_ea @ W1 + b1), CSR-ordered, E x 128 ----------------
__launch_bounds__(256, 4)
__global__ void k_hmlp(const float* __restrict__ es_ea, const float* __restrict__ W1,
                       const float* __restrict__ b1, float* __restrict__ H){
  const int pc = threadIdx.x & 31, er = threadIdx.x >> 5;
  const size_t e = (size_t)blockIdx.x*8 + er;
  float4 w1v[16];
  #pragma unroll
  for(int i=0;i<16;i++) w1v[i] = *(const float4*)&W1[i*128 + pc*4];
  float4 hv = *(const float4*)&b1[pc*4];
  float eav[16];
  const float4* eap = (const float4*)(es_ea + e*16);
  #pragma unroll
  for(int q=0;q<4;q++){
    float4 v = eap[q];
    eav[q*4+0]=v.x; eav[q*4+1]=v.y; eav[q*4+2]=v.z; eav[q*4+3]=v.w;
  }
  #pragma unroll
  for(int i=0;i<16;i++){
    hv.x += eav[i]*w1v[i].x;
    hv.y += eav[i]*w1v[i].y;
    hv.z += eav[i]*w1v[i].z;
    hv.w += eav[i]*w1v[i].w;
  }
  hv.x = fmaxf(hv.x,0.f); hv.y = fmaxf(hv.y,0.f);
  hv.z = fmaxf(hv.z,0.f); hv.w = fmaxf(hv.w,0.f);
  *(float4*)&H[e*128 + pc*4] = hv;
}

// ---------------- xbar[n,i] = mean over in-edges of x[src,i] ----------------
template<int IC>
__global__ void k_xbar(const float* __restrict__ x, const int* __restrict__ es_src,
                       const int* __restrict__ row_start, float* __restrict__ xbar){
  constexpr int TI = IC/16;
  const int wid = threadIdx.x>>6, lane = threadIdx.x&63;
  const int n = blockIdx.x*4 + wid;
  const int eg = lane>>4, ig = lane&15;
  const int a = row_start[n], b = row_start[n+1];
  float s[TI];
  #pragma unroll
  for(int u=0;u<TI;u++) s[u]=0.f;
  for(int e=a+eg; e<b; e+=4){
    int sn = es_src[e];
    #pragma unroll
    for(int u=0;u<TI;u++) s[u] += x[(size_t)sn*IC + ig*TI + u];
  }
  #pragma unroll
  for(int u=0;u<TI;u++){
    s[u] += __shfl_xor(s[u], 16, 64);
    s[u] += __shfl_xor(s[u], 32, 64);
  }
  if(eg==0){
    float dinv = 1.f/fmaxf((float)(b-a), 1.f);
    #pragma unroll
    for(int u=0;u<TI;u++) xbar[(size_t)n*IC + ig*TI + u] = s[u]*dinv;
  }
}

// ---------------- fused NNConv layer: async-staged register scatter + GEMM ----------------
// Thread tile (scatter): tid < ACT=(PLEN/PP)*(IC/4); pw=tid/NPW owns PP p-values,
// iw=tid%NPW owns 4 i-values (b128 x reads). acc[BN][PP][4] <= 48 floats (spill rule).
// Staging via global_load_lds(16B) into LDS aliased over S. GEMM: kq=tid&31 k-split,
// oq=tid>>5 o-group of TO=OC/8; shuffle-reduce over 32 kq lanes.
template<int IC, int OC, int PLEN, int KS, int BN, int PP>
__launch_bounds__(256, 4)
__global__ void k_layer(const float* __restrict__ x_in, const float* __restrict__ H,
                        const int* __restrict__ es_src, const int* __restrict__ row_start,
                        const float* __restrict__ W2, float* __restrict__ part)
{
  constexpr int K   = PLEN*IC;
  constexpr int HV4 = PLEN/4;
  constexpr int XV  = IC/4;
  constexpr int NPW = IC/4;            // iw groups (TI=4)
  constexpr int ACT = (PLEN/PP)*NPW;   // active scatter threads
  constexpr int TO  = OC/8;
  constexpr int J   = K/128;           // GEMM iters (KQ=32, 4 k per read)
  static_assert(BN*PP*4 <= 48, "spill-safe accumulator");
  static_assert(BN*K >= EB*(PLEN+IC), "staging alias fits in S");
  static_assert(ACT <= 256 && (K%128)==0, "tiling");

  __shared__ __align__(16) float S[BN*K];
  __shared__ int rs_s[BN+1], ro[BN+1];

  float* hb = S;                 // EB*PLEN staged H slice
  float* xs = S + EB*PLEN;       // EB*IC staged x[src]
  float4* hb4 = (float4*)hb;
  float4* xs4 = (float4*)xs;

  const int tid = threadIdx.x;
  const int wid = tid>>6, lane = tid&63;
  const int split = blockIdx.x % KS;
  const int nb = blockIdx.x / KS;
  const int n0 = nb*BN;
  const int p04 = split*HV4;     // float4 offset into 32-f4 H row

  if(tid<=BN) rs_s[tid] = row_start[min(n0+tid, NN)];
  __syncthreads();
  const int estart = rs_s[0], eend = rs_s[BN];

  const int pw = tid / NPW;
  const int iw = tid - pw*NPW;

  float acc[BN][PP][4];
  #pragma unroll
  for(int n=0;n<BN;n++)
    #pragma unroll
    for(int p=0;p<PP;p++)
      #pragma unroll
      for(int u=0;u<4;u++) acc[n][p][u]=0.f;

  const float4* H4 = (const float4*)H;
  const float4* x4 = (const float4*)x_in;

  for(int bstart=estart; bstart<eend; bstart+=EB){
    const int ebc = min(EB, eend-bstart);
    if(tid<=BN){ int v = rs_s[tid]-bstart; ro[tid] = min(max(v,0), ebc); }
    // async stage H slice (coalesced stream)
    const int nH = ebc*HV4;
    for(int s0 = wid*64; s0 < nH; s0 += 256){
      int s = s0 + lane;
      if(s < nH){
        int e = s/HV4, q = s - e*HV4;
        gl_lds16(H4 + ((size_t)(bstart+e)*32 + p04 + q), hb4 + s0);
      }
    }
    // async stage x[src] (gather)
    const int nX = ebc*XV;
    for(int s0 = wid*64; s0 < nX; s0 += 256){
      int s = s0 + lane;
      if(s < nX){
        int e = s/XV, q = s - e*XV;
        int sn = es_src[bstart+e];
        gl_lds16(x4 + ((size_t)sn*XV + q), xs4 + s0);
      }
    }
    asm volatile("s_waitcnt vmcnt(0)" ::: "memory");
    __syncthreads();
    // scatter into register accumulators
    if(tid < ACT){
      #pragma unroll
      for(int nl=0; nl<BN; nl++){
        const int a = ro[nl], b = ro[nl+1];
        for(int e=a; e<b; e++){
          float hv[PP];
          if constexpr (PP==4){
            float4 h = *(const float4*)&hb[e*PLEN + pw*4];
            hv[0]=h.x; hv[1]=h.y; hv[2]=h.z; hv[3]=h.w;
          } else {
            float2 h = *(const float2*)&hb[e*PLEN + pw*2];
            hv[0]=h.x; hv[1]=h.y;
          }
          float4 xv = *(const float4*)&xs[e*IC + iw*4];
          #pragma unroll
          for(int p=0;p<PP;p++){
            acc[nl][p][0] += hv[p]*xv.x;
            acc[nl][p][1] += hv[p]*xv.y;
            acc[nl][p][2] += hv[p]*xv.z;
            acc[nl][p][3] += hv[p]*xv.w;
          }
        }
      }
    }
    __syncthreads();
  }

  // dump scaled S (b128 per (n,p); staging area dead)
  if(tid < ACT){
    #pragma unroll
    for(int n=0;n<BN;n++){
      const float dv = 1.f/fmaxf((float)(rs_s[n+1]-rs_s[n]), 1.f);
      #pragma unroll
      for(int p=0;p<PP;p++){
        float4 v = make_float4(acc[n][p][0]*dv, acc[n][p][1]*dv,
                               acc[n][p][2]*dv, acc[n][p][3]*dv);
        *(float4*)&S[(n*PLEN + pw*PP + p)*IC + iw*4] = v;
      }
    }
  }
  __syncthreads();

  // ---- GEMM: part[split][n][o] = sum_k S[n][k] * W2[split*K + k][o] ----
  const int kq = tid & 31;
  const int oq = tid >> 5;
  const int o0 = oq*TO;
  const float* W2b = W2 + (size_t)split*K*OC + o0;
  float outp[BN][TO];
  #pragma unroll
  for(int n=0;n<BN;n++)
    #pragma unroll
    for(int t=0;t<TO;t++) outp[n][t]=0.f;

  for(int j=0;j<J;j++){
    const int k4 = j*32 + kq;
    float wv[4][TO];
    #pragma unroll
    for(int r=0;r<4;r++){
      const float* wr = W2b + (size_t)(4*k4+r)*OC;
      if constexpr (TO==6){
        float2 a=*(const float2*)wr, b=*(const float2*)(wr+2), c=*(const float2*)(wr+4);
        wv[r][0]=a.x; wv[r][1]=a.y; wv[r][2]=b.x; wv[r][3]=b.y; wv[r][4]=c.x; wv[r][5]=c.y;
      } else if constexpr (TO==4){
        float4 a=*(const float4*)wr;
        wv[r][0]=a.x; wv[r][1]=a.y; wv[r][2]=a.z; wv[r][3]=a.w;
      } else {
        float2 a=*(const float2*)wr;
        wv[r][0]=a.x; wv[r][1]=a.y;
      }
    }
    #pragma unroll
    for(int n=0;n<BN;n++){
      float4 sv = *(const float4*)&S[n*K + 4*k4];
      #pragma unroll
      for(int t=0;t<TO;t++)
        outp[n][t] += sv.x*wv[0][t] + sv.y*wv[1][t] + sv.z*wv[2][t] + sv.w*wv[3][t];
    }
  }
  // reduce over 32 kq lanes (within each 32-lane half)
  #pragma unroll
  for(int m=16; m>=1; m>>=1)
    #pragma unroll
    for(int n=0;n<BN;n++)
      #pragma unroll
      for(int t=0;t<TO;t++) outp[n][t] += __shfl_xor(outp[n][t], m, 64);

  if(kq==0){
    #pragma unroll
    for(int n=0;n<BN;n++){
      if(n0+n < NN){
        float* dst = part + ((size_t)split*NN + n0+n)*OC + o0;
        #pragma unroll
        for(int t=0;t<TO;t++) dst[t] = outp[n][t];
      }
    }
  }
}

// ---------------- epilogue: y = relu(sum_s part[s] + x@root + xbar@b2 + bias) ----------------
template<int IC, int OC, int KS>
__global__ void k_epi(const float* __restrict__ part, const float* __restrict__ x,
                      const float* __restrict__ xbar,
                      const float* __restrict__ root, const float* __restrict__ b2,
                      const float* __restrict__ bias, float* __restrict__ y)
{
  int idx = blockIdx.x*256 + threadIdx.x;
  if(idx >= NN*OC) return;
  int n = idx/OC, o = idx - n*OC;
  float v = bias[o];
  #pragma unroll
  for(int s=0;s<KS;s++) v += part[(size_t)s*NN*OC + idx];
  #pragma unroll
  for(int i=0;i<IC;i++) v += x[(size_t)n*IC+i]*root[i*OC+o];
  #pragma unroll
  for(int i=0;i<IC;i++) v += xbar[(size_t)n*IC+i]*b2[i*OC+o];
  y[idx] = fmaxf(v, 0.f);
}

// ---------------- set2set (2 steps) + final MLP, one wave per graph ----------------
__global__ void k_s2s(const float* __restrict__ xg, const int* __restrict__ batch,
  const float* __restrict__ Wih, const float* __restrict__ Whh,
  const float* __restrict__ bih, const float* __restrict__ bhh,
  const float* __restrict__ l1W, const float* __restrict__ l1b,
  const float* __restrict__ l2W, const float* __restrict__ l2b,
  const float* __restrict__ lfW, const float* __restrict__ lfb,
  float* __restrict__ out)
{
  int g = blockIdx.x, lane = threadIdx.x;
  __shared__ float hs[16], cs[16], qs[32], gs[64], rs[16];
  int r0 = lowerb(batch, NN, g);
  int r1 = lowerb(batch, NN, g+1);
  if(lane<16){ hs[lane]=0.f; cs[lane]=0.f; }
  if(lane<32) qs[lane]=0.f;
  __syncthreads();
  for(int step=0; step<2; step++){
    float gate = bih[lane] + bhh[lane];
    for(int k=0;k<32;k++) gate += qs[k]*Wih[lane*32+k];
    for(int k=0;k<16;k++) gate += hs[k]*Whh[lane*16+k];
    gs[lane] = gate;
    __syncthreads();
    if(lane<16){
      float ig = 1.f/(1.f+expf(-gs[lane]));
      float fg = 1.f/(1.f+expf(-gs[lane+16]));
      float gg = tanhf(gs[lane+32]);
      float og = 1.f/(1.f+expf(-gs[lane+48]));
      float cn = fg*cs[lane] + ig*gg;
      cs[lane] = cn;
      hs[lane] = og*tanhf(cn);
    }
    __syncthreads();
    float m = -1e30f;
    for(int n=r0+lane; n<r1; n+=64){
      float e=0.f;
      for(int k=0;k<16;k++) e += xg[n*16+k]*hs[k];
      m = fmaxf(m, e);
    }
    for(int d=1; d<64; d<<=1) m = fmaxf(m, __shfl_xor(m, d));
    float ssum = 0.f;
    float racc[16];
    #pragma unroll
    for(int k=0;k<16;k++) racc[k]=0.f;
    for(int n=r0+lane; n<r1; n+=64){
      float e=0.f, xv[16];
      #pragma unroll
      for(int k=0;k<16;k++){ xv[k]=xg[n*16+k]; e += xv[k]*hs[k]; }
      float a = expf(e - m);
      ssum += a;
      #pragma unroll
      for(int k=0;k<16;k++) racc[k] += a*xv[k];
    }
    for(int d=1; d<64; d<<=1) ssum += __shfl_xor(ssum, d);
    #pragma unroll
    for(int k=0;k<16;k++)
      for(int d=1; d<64; d<<=1) racc[k] += __shfl_xor(racc[k], d);
    ssum = fmaxf(ssum, 1e-16f);
    if(lane==0){
      #pragma unroll
      for(int k=0;k<16;k++) rs[k] = racc[k]/ssum;
    }
    __syncthreads();
    if(lane<16){ qs[lane]=hs[lane]; qs[16+lane]=rs[lane]; }
    __syncthreads();
  }
  if(lane<16){
    float v = l1b[lane];
    for(int k=0;k<32;k++) v += qs[k]*l1W[k*16+lane];
    gs[lane] = fmaxf(v,0.f);
  }
  __syncthreads();
  if(lane<8){
    float v = l2b[lane];
    for(int k=0;k<16;k++) v += gs[k]*l2W[k*8+lane];
    gs[32+lane] = fmaxf(v,0.f);
  }
  __syncthreads();
  if(lane==0){
    float v = lfb[0];
    for(int k=0;k<8;k++) v += gs[32+k]*lfW[k];
    out[g] = v;
  }
}

extern "C" void kernel_launch(void* const* d_in, const int* in_sizes, int n_in,
                              void* d_out, int out_size, void* d_ws, size_t ws_size,
                              hipStream_t stream) {
  const float* x0   = (const float*)d_in[0];
  const int*   ei   = (const int*)d_in[1];
  const float* ea   = (const float*)d_in[2];
  const int*   batch= (const int*)d_in[3];
  const float* c1W1 = (const float*)d_in[4];  const float* c1b1 = (const float*)d_in[5];
  const float* c1W2 = (const float*)d_in[6];  const float* c1b2 = (const float*)d_in[7];
  const float* c1rt = (const float*)d_in[8];  const float* c1bs = (const float*)d_in[9];
  const float* c2W1 = (const float*)d_in[10]; const float* c2b1 = (const float*)d_in[11];
  const float* c2W2 = (const float*)d_in[12]; const float* c2b2 = (const float*)d_in[13];
  const float* c2rt = (const float*)d_in[14]; const float* c2bs = (const float*)d_in[15];
  const float* c3W1 = (const float*)d_in[16]; const float* c3b1 = (const float*)d_in[17];
  const float* c3W2 = (const float*)d_in[18]; const float* c3b2 = (const float*)d_in[19];
  const float* c3rt = (const float*)d_in[20]; const float* c3bs = (const float*)d_in[21];
  const float* Wih  = (const float*)d_in[22]; const float* Whh  = (const float*)d_in[23];
  const float* bih  = (const float*)d_in[24]; const float* bhh  = (const float*)d_in[25];
  const float* l1W  = (const float*)d_in[26]; const float* l1b  = (const float*)d_in[27];
  const float* l2W  = (const float*)d_in[28]; const float* l2b  = (const float*)d_in[29];
  const float* lfW  = (const float*)d_in[30]; const float* lfb  = (const float*)d_in[31];
  float* out = (float*)d_out;

  const int* src = ei;
  const int* tgt = ei + NE;

  // workspace carve (~140 MB)
  char* w = (char*)d_ws;
  auto carve = [&](size_t bytes)->void*{ void* p = (void*)w; w += (bytes + 255) & ~(size_t)255; return p; };
  int*   row_start = (int*)carve((NN+1)*sizeof(int));
  int*   cur       = (int*)carve(NN*sizeof(int));
  int*   es_src    = (int*)carve(NE*sizeof(int));
  int*   es_pos    = (int*)carve(NE*sizeof(int));
  float* es_ea     = (float*)carve((size_t)NE*16*sizeof(float));
  float* Hbuf      = (float*)carve((size_t)NE*128*sizeof(float));
  float* xbar      = (float*)carve((size_t)NN*48*sizeof(float));
  float* y1   = (float*)carve((size_t)NN*48*sizeof(float));
  float* y2   = (float*)carve((size_t)NN*32*sizeof(float));
  float* y3   = (float*)carve((size_t)NN*16*sizeof(float));
  float* part = (float*)carve((size_t)4*NN*48*sizeof(float));

  // ---- CSR by tgt + ea gather
  hipMemsetAsync(cur, 0, NN*sizeof(int), stream);
  k_count<<<(NE+255)/256, 256, 0, stream>>>(tgt, cur);
  k_scan<<<1, 1024, 0, stream>>>(cur, row_start);
  hipMemsetAsync(cur, 0, NN*sizeof(int), stream);
  k_place<<<(NE+255)/256, 256, 0, stream>>>(src, tgt, row_start, cur, es_src, es_pos);
  k_gatherea<<<(NE+255)/256, 256, 0, stream>>>(ea, es_pos, es_ea);

  const int NB6 = (NN+5)/6;   // 3334
  const int NB3 = (NN+2)/3;   // 6667

  // ---- layer 1: IC=16 OC=48 | PLEN=64 KS=2 BN=6 PP=2 (ACT=128, TO=6)
  k_hmlp<<<NE/8, 256, 0, stream>>>(es_ea, c1W1, c1b1, Hbuf);
  k_xbar<16><<<NN/4, 256, 0, stream>>>(x0, es_src, row_start, xbar);
  k_layer<16,48,64,2,6,2><<<NB6*2, 256, 0, stream>>>(x0, Hbuf, es_src, row_start, c1W2, part);
  k_epi<16,48,2><<<(NN*48+255)/256, 256, 0, stream>>>(part, x0, xbar, c1rt, c1b2, c1bs, y1);

  // ---- layer 2: IC=48 OC=32 | PLEN=32 KS=4 BN=6 PP=2 (ACT=192, TO=4)
  k_hmlp<<<NE/8, 256, 0, stream>>>(es_ea, c2W1, c2b1, Hbuf);
  k_xbar<48><<<NN/4, 256, 0, stream>>>(y1, es_src, row_start, xbar);
  k_layer<48,32,32,4,6,2><<<NB6*4, 256, 0, stream>>>(y1, Hbuf, es_src, row_start, c2W2, part);
  k_epi<48,32,4><<<(NN*32+255)/256, 256, 0, stream>>>(part, y1, xbar, c2rt, c2b2, c2bs, y2);

  // ---- layer 3: IC=32 OC=16 | PLEN=64 KS=2 BN=3 PP=4 (ACT=128, TO=2)
  k_hmlp<<<NE/8, 256, 0, stream>>>(es_ea, c3W1, c3b1, Hbuf);
  k_xbar<32><<<NN/4, 256, 0, stream>>>(y2, es_src, row_start, xbar);
  k_layer<32,16,64,2,3,4><<<NB3*2, 256, 0, stream>>>(y2, Hbuf, es_src, row_start, c3W2, part);
  k_epi<32,16,2><<<(NN*16+255)/256, 256, 0, stream>>>(part, y2, xbar, c3rt, c3b2, c3bs, y3);

  // ---- set2set + MLP head
  k_s2s<<<NG, 64, 0, stream>>>(y3, batch, Wih, Whh, bih, bhh, l1W, l1b, l2W, l2b, lfW, lfb, out);
}